// Round 1
// baseline (341.214 us; speedup 1.0000x reference)
//
#include <hip/hip_runtime.h>

#define DEVI __device__ __forceinline__

typedef short bf16x8 __attribute__((ext_vector_type(8)));   // 8 bf16 (4 VGPR) MFMA frag
typedef float f32x4 __attribute__((ext_vector_type(4)));
typedef unsigned short u16x8 __attribute__((ext_vector_type(8)));

static constexpr int S_LEN = 2048;
static constexpr int DMODEL = 1024;
static constexpr int NH = 16;
static constexpr int DK = 64;

// round-to-nearest-even fp32 -> bf16 bits
DEVI unsigned short f2bf(float f) {
  unsigned int u = __builtin_bit_cast(unsigned int, f);
  u = u + 0x7fffu + ((u >> 16) & 1u);
  return (unsigned short)(u >> 16);
}

typedef __attribute__((address_space(3))) unsigned int lds_u32;
typedef __attribute__((address_space(1))) const unsigned int glb_u32;

// async global->LDS, 16B per lane; lds dest = wave-uniform base + lane*16
DEVI void gload16(const void* g, void* lds) {
  __builtin_amdgcn_global_load_lds((glb_u32*)reinterpret_cast<uintptr_t>(g),
                                   (lds_u32*)reinterpret_cast<uintptr_t>(lds),
                                   16, 0, 0);
}

// ---------------- fp32 -> bf16 convert (8 elems/thread) ----------------
__global__ __launch_bounds__(256) void cvt_f32_bf16(const float* __restrict__ in,
                                                    unsigned short* __restrict__ out,
                                                    int n8) {
  int i = blockIdx.x * 256 + threadIdx.x;
  if (i >= n8) return;
  const float4* p = (const float4*)in + (size_t)i * 2;
  float4 a = p[0], b = p[1];
  u16x8 o;
  o[0] = f2bf(a.x); o[1] = f2bf(a.y); o[2] = f2bf(a.z); o[3] = f2bf(a.w);
  o[4] = f2bf(b.x); o[5] = f2bf(b.y); o[6] = f2bf(b.z); o[7] = f2bf(b.w);
  *((u16x8*)out + i) = o;
}

// ---------------- projection GEMM: C[m,n] = sum_k X[m,k]*W[n,k] + bias[n] ----
// X: [8192,1024] bf16, W: [1024,1024] bf16 (BT form). Output scattered to
// head layout [B,H,S,DK] bf16. 128x128 tile, BK=32, 256 thr (4 waves 2x2).
__global__ __launch_bounds__(256) void proj_gemm(const unsigned short* __restrict__ A,
                                                 const unsigned short* __restrict__ W,
                                                 const float* __restrict__ bias,
                                                 unsigned short* __restrict__ C) {
  __shared__ unsigned short As[128 * 32];  // row-major [row][k], 64B rows (linear for gload)
  __shared__ unsigned short Bs[128 * 32];
  const int m0 = blockIdx.x * 128, n0 = blockIdx.y * 128;
  const int tid = threadIdx.x, wid = tid >> 6, lane = tid & 63;
  const int l15 = lane & 15, lg = lane >> 4;
  const int mb = (wid >> 1) * 64, nb = (wid & 1) * 64;

  f32x4 acc[4][4] = {};

  for (int kk = 0; kk < 32; ++kk) {
    const int k0 = kk * 32;  // element offset in K
#pragma unroll
    for (int i = 0; i < 2; ++i) {
      const int jbase = (wid * 2 + i) * 1024;      // byte base in 8KB tile
      const int o = jbase + lane * 16;             // this lane's byte offset
      const int row = o >> 6, inner = o & 63;      // 64B per row (32 bf16)
      gload16((const char*)A + (size_t)(m0 + row) * 2048 + k0 * 2 + inner,
              (char*)As + jbase);
      gload16((const char*)W + (size_t)(n0 + row) * 2048 + k0 * 2 + inner,
              (char*)Bs + jbase);
    }
    __syncthreads();

    bf16x8 af[4], bfr[4];
#pragma unroll
    for (int ms = 0; ms < 4; ++ms)
      af[ms] = *(const bf16x8*)&As[(mb + ms * 16 + l15) * 32 + lg * 8];
#pragma unroll
    for (int ns = 0; ns < 4; ++ns)
      bfr[ns] = *(const bf16x8*)&Bs[(nb + ns * 16 + l15) * 32 + lg * 8];
#pragma unroll
    for (int ms = 0; ms < 4; ++ms)
#pragma unroll
      for (int ns = 0; ns < 4; ++ns)
        acc[ms][ns] = __builtin_amdgcn_mfma_f32_16x16x32_bf16(af[ms], bfr[ns],
                                                              acc[ms][ns], 0, 0, 0);
    __syncthreads();
  }

  // epilogue: scatter to [B,H,S,DK] bf16 (+bias). C row=(lg*4+r), col=l15 per frag.
#pragma unroll
  for (int ms = 0; ms < 4; ++ms) {
#pragma unroll
    for (int ns = 0; ns < 4; ++ns) {
      const int n = n0 + nb + ns * 16 + l15;
      const float bv = bias[n];
#pragma unroll
      for (int r = 0; r < 4; ++r) {
        const int m = m0 + mb + ms * 16 + lg * 4 + r;
        const size_t oi =
            (((size_t)(m >> 11) * NH + (n >> 6)) * S_LEN + (m & 2047)) * DK + (n & 63);
        C[oi] = f2bf(acc[ms][ns][r] + bv);
      }
    }
  }
}

// ---------------- V transpose: [bh][s][dk] -> [bh][dk][s] -------------------
__global__ __launch_bounds__(256) void transpose_v(const unsigned short* __restrict__ V,
                                                   unsigned short* __restrict__ Vt) {
  const int bh = blockIdx.y, st = blockIdx.x;  // 64 bh x 32 s-tiles of 64
  const unsigned short* Vb = V + (size_t)bh * S_LEN * DK;
  unsigned short* Vtb = Vt + (size_t)bh * DK * S_LEN;
  __shared__ unsigned short T[64][72];
  const int t = threadIdx.x;
  const int row = t >> 2, seg = (t & 3) * 16;
  const uint4* src = (const uint4*)(Vb + (size_t)(st * 64 + row) * DK + seg);
  uint4 v0 = src[0], v1 = src[1];
  *(uint4*)&T[row][seg] = v0;
  *(uint4*)&T[row][seg + 8] = v1;
  __syncthreads();
  union { unsigned short u[16]; uint4 q[2]; } tmp;
#pragma unroll
  for (int j = 0; j < 16; ++j) tmp.u[j] = T[seg + j][row];
  uint4* dst = (uint4*)(Vtb + (size_t)row * S_LEN + st * 64 + seg);
  dst[0] = tmp.q[0];
  dst[1] = tmp.q[1];
}

// ---------------- flash attention -------------------------------------------
// grid: (32 q-tiles, 64 bh). 4 waves x 16 q-rows, KVBLK=64, Dk=64.
__global__ __launch_bounds__(256) void attn_fwd(const unsigned short* __restrict__ Q,
                                                const unsigned short* __restrict__ K,
                                                const unsigned short* __restrict__ Vt,
                                                float* __restrict__ Out) {
  const int bh = blockIdx.y, qt = blockIdx.x;
  const unsigned short* Qb = Q + (size_t)bh * S_LEN * DK;
  const unsigned short* Kb = K + (size_t)bh * S_LEN * DK;
  const unsigned short* Vb = Vt + (size_t)bh * DK * S_LEN;
  const int b = bh >> 4, h = bh & 15;
  float* Ob = Out + (size_t)b * S_LEN * DMODEL + h * DK;

  __shared__ unsigned short Ks[64 * 72];  // [j][dk], padded rows (144B)
  __shared__ unsigned short Vs[64 * 72];  // [dk][j], padded
  __shared__ unsigned short Ps[64 * 72];  // [q][j], padded

  const int tid = threadIdx.x, wid = tid >> 6, lane = tid & 63;
  const int l15 = lane & 15, lg = lane >> 4;
  const int q0 = qt * 64;

  // Q fragments held in registers for the whole KV loop (A-frag layout)
  bf16x8 qf[2];
  {
    const unsigned short* qrow = Qb + (size_t)(q0 + wid * 16 + l15) * DK + lg * 8;
    qf[0] = *(const bf16x8*)qrow;
    qf[1] = *(const bf16x8*)(qrow + 32);
  }

  f32x4 oacc[4] = {};
  float m_r[4], l_r[4];
#pragma unroll
  for (int r = 0; r < 4; ++r) { m_r[r] = -1e30f; l_r[r] = 0.f; }

  const int srow = tid >> 2, sseg = (tid & 3) * 16;  // staging: 64 rows x 64, 16 el/thr

  for (int it = 0; it < 32; ++it) {
    const int j0 = it * 64;
    // stage K tile [64][64] and Vt tile [64][64] into padded LDS
    {
      const uint4* sk = (const uint4*)(Kb + (size_t)(j0 + srow) * DK + sseg);
      uint4 a = sk[0], c = sk[1];
      *(uint4*)&Ks[srow * 72 + sseg] = a;
      *(uint4*)&Ks[srow * 72 + sseg + 8] = c;
      const uint4* sv = (const uint4*)(Vb + (size_t)srow * S_LEN + j0 + sseg);
      uint4 d = sv[0], e = sv[1];
      *(uint4*)&Vs[srow * 72 + sseg] = d;
      *(uint4*)&Vs[srow * 72 + sseg + 8] = e;
    }
    __syncthreads();

    // scores S[16q][64j] per wave
    f32x4 sacc[4] = {};
#pragma unroll
    for (int ns = 0; ns < 4; ++ns) {
      bf16x8 kb0 = *(const bf16x8*)&Ks[(ns * 16 + l15) * 72 + lg * 8];
      bf16x8 kb1 = *(const bf16x8*)&Ks[(ns * 16 + l15) * 72 + 32 + lg * 8];
      sacc[ns] = __builtin_amdgcn_mfma_f32_16x16x32_bf16(qf[0], kb0, sacc[ns], 0, 0, 0);
      sacc[ns] = __builtin_amdgcn_mfma_f32_16x16x32_bf16(qf[1], kb1, sacc[ns], 0, 0, 0);
    }

    // online softmax; row = wid*16 + lg*4 + r, 16 lanes (same lg) hold one row
#pragma unroll
    for (int r = 0; r < 4; ++r) {
      float t = fmaxf(fmaxf(sacc[0][r], sacc[1][r]), fmaxf(sacc[2][r], sacc[3][r]));
      t *= 0.125f;
      t = fmaxf(t, __shfl_xor(t, 1));
      t = fmaxf(t, __shfl_xor(t, 2));
      t = fmaxf(t, __shfl_xor(t, 4));
      t = fmaxf(t, __shfl_xor(t, 8));
      const float mn = fmaxf(m_r[r], t);
      const float esc = __expf(m_r[r] - mn);
      m_r[r] = mn;
      float ps = 0.f;
#pragma unroll
      for (int ns = 0; ns < 4; ++ns) {
        const float p = __expf(sacc[ns][r] * 0.125f - mn);
        ps += p;
        Ps[(wid * 16 + lg * 4 + r) * 72 + ns * 16 + l15] = f2bf(p);
        oacc[ns][r] *= esc;
      }
      ps += __shfl_xor(ps, 1);
      ps += __shfl_xor(ps, 2);
      ps += __shfl_xor(ps, 4);
      ps += __shfl_xor(ps, 8);
      l_r[r] = l_r[r] * esc + ps;
    }

    // PV: O[16q][64dk] += P[16q][64j] * V[64j][64dk]  (B from Vt rows)
    bf16x8 pa0 = *(const bf16x8*)&Ps[(wid * 16 + l15) * 72 + lg * 8];
    bf16x8 pa1 = *(const bf16x8*)&Ps[(wid * 16 + l15) * 72 + 32 + lg * 8];
#pragma unroll
    for (int ns = 0; ns < 4; ++ns) {
      bf16x8 vb0 = *(const bf16x8*)&Vs[(ns * 16 + l15) * 72 + lg * 8];
      bf16x8 vb1 = *(const bf16x8*)&Vs[(ns * 16 + l15) * 72 + 32 + lg * 8];
      oacc[ns] = __builtin_amdgcn_mfma_f32_16x16x32_bf16(pa0, vb0, oacc[ns], 0, 0, 0);
      oacc[ns] = __builtin_amdgcn_mfma_f32_16x16x32_bf16(pa1, vb1, oacc[ns], 0, 0, 0);
    }
    __syncthreads();
  }

  // normalize + store fp32 in merged-head layout [b][q][h*64+dk]
#pragma unroll
  for (int r = 0; r < 4; ++r) {
    const float inv = 1.f / l_r[r];
    const int qg = q0 + wid * 16 + lg * 4 + r;
    float* op = Ob + (size_t)qg * DMODEL;
#pragma unroll
    for (int ns = 0; ns < 4; ++ns) op[ns * 16 + l15] = oacc[ns][r] * inv;
  }
}

// ---------------- host launch ------------------------------------------------
extern "C" void kernel_launch(void* const* d_in, const int* in_sizes, int n_in,
                              void* d_out, int out_size, void* d_ws, size_t ws_size,
                              hipStream_t stream) {
  (void)in_sizes; (void)n_in; (void)out_size; (void)ws_size;
  const float* q_in = (const float*)d_in[0];
  const float* k_in = (const float*)d_in[1];
  const float* v_in = (const float*)d_in[2];
  const float* Wq = (const float*)d_in[3];
  const float* bq = (const float*)d_in[4];
  const float* Wk = (const float*)d_in[5];
  const float* bk = (const float*)d_in[6];
  const float* Wv = (const float*)d_in[7];
  const float* bv = (const float*)d_in[8];
  float* out = (float*)d_out;

  char* ws = (char*)d_ws;
  unsigned short* Xbf = (unsigned short*)(ws);                    // 16 MB
  unsigned short* Wbf = (unsigned short*)(ws + 16777216);         // 2 MB
  unsigned short* Qh  = (unsigned short*)(ws + 18874368);         // 16 MB
  unsigned short* Kh  = Qh + 8388608;                             // 16 MB
  unsigned short* Vh  = Kh + 8388608;                             // 16 MB
  unsigned short* Vt  = Vh + 8388608;                             // 16 MB

  const int nX8 = (4 * S_LEN * DMODEL) / 8;   // 1048576
  const int nW8 = (DMODEL * DMODEL) / 8;      // 131072
  const dim3 gGemm(64, 8), gBh(32, 64);

  cvt_f32_bf16<<<4096, 256, 0, stream>>>(q_in, Xbf, nX8);
  cvt_f32_bf16<<<512, 256, 0, stream>>>(Wq, Wbf, nW8);
  proj_gemm<<<gGemm, 256, 0, stream>>>(Xbf, Wbf, bq, Qh);

  cvt_f32_bf16<<<4096, 256, 0, stream>>>(k_in, Xbf, nX8);
  cvt_f32_bf16<<<512, 256, 0, stream>>>(Wk, Wbf, nW8);
  proj_gemm<<<gGemm, 256, 0, stream>>>(Xbf, Wbf, bk, Kh);

  cvt_f32_bf16<<<4096, 256, 0, stream>>>(v_in, Xbf, nX8);
  cvt_f32_bf16<<<512, 256, 0, stream>>>(Wv, Wbf, nW8);
  proj_gemm<<<gGemm, 256, 0, stream>>>(Xbf, Wbf, bv, Vh);

  transpose_v<<<gBh, 256, 0, stream>>>(Vh, Vt);
  attn_fwd<<<gBh, 256, 0, stream>>>(Qh, Kh, Vt, out);
}

// Round 2
// 223.756 us; speedup vs baseline: 1.5249x; 1.5249x over previous
//
#include <hip/hip_runtime.h>

#define DEVI __device__ __forceinline__

typedef short bf16x8 __attribute__((ext_vector_type(8)));   // 8 bf16 (4 VGPR) MFMA frag
typedef float f32x4 __attribute__((ext_vector_type(4)));
typedef float f32x16 __attribute__((ext_vector_type(16)));
typedef unsigned short u16x8 __attribute__((ext_vector_type(8)));
typedef unsigned int u32x2 __attribute__((ext_vector_type(2)));
typedef int i32x4 __attribute__((ext_vector_type(4)));

static constexpr int S_LEN = 2048;
static constexpr int DMODEL = 1024;
static constexpr int NH = 16;
static constexpr int DK = 64;

// round-to-nearest-even fp32 -> bf16 bits
DEVI unsigned short f2bf(float f) {
  unsigned int u = __builtin_bit_cast(unsigned int, f);
  u = u + 0x7fffu + ((u >> 16) & 1u);
  return (unsigned short)(u >> 16);
}
DEVI unsigned cvtpk(float lo, float hi) {
  unsigned d;
  asm("v_cvt_pk_bf16_f32 %0, %1, %2" : "=v"(d) : "v"(lo), "v"(hi));
  return d;
}
DEVI float bitf(unsigned u) { return __builtin_bit_cast(float, u); }
DEVI unsigned bitu(float f) { return __builtin_bit_cast(unsigned, f); }

typedef __attribute__((address_space(3))) unsigned int lds_u32;
typedef __attribute__((address_space(1))) const unsigned int glb_u32;

// async global->LDS, 16B per lane; lds dest = wave-uniform base + lane*16
DEVI void gload16(const void* g, void* lds) {
  __builtin_amdgcn_global_load_lds((glb_u32*)reinterpret_cast<uintptr_t>(g),
                                   (lds_u32*)reinterpret_cast<uintptr_t>(lds),
                                   16, 0, 0);
}

// ---------------- fp32 -> bf16 convert (8 elems/thread) ----------------
__global__ __launch_bounds__(256) void cvt_f32_bf16(const float* __restrict__ in,
                                                    unsigned short* __restrict__ out,
                                                    int n8) {
  int i = blockIdx.x * 256 + threadIdx.x;
  if (i >= n8) return;
  const float4* p = (const float4*)in + (size_t)i * 2;
  float4 a = p[0], b = p[1];
  u16x8 o;
  o[0] = f2bf(a.x); o[1] = f2bf(a.y); o[2] = f2bf(a.z); o[3] = f2bf(a.w);
  o[4] = f2bf(b.x); o[5] = f2bf(b.y); o[6] = f2bf(b.z); o[7] = f2bf(b.w);
  *((u16x8*)out + i) = o;
}

// ---------------- projection GEMM: C[m,n] = (sum_k X[m,k]*W[n,k] + bias[n])*scale
// X: [8192,1024] bf16, W: [1024,1024] bf16 (BT form). Output scattered to
// head layout [B,H,S,DK] bf16. 128x128 tile, BK=32, 256 thr (4 waves 2x2).
__global__ __launch_bounds__(256) void proj_gemm(const unsigned short* __restrict__ A,
                                                 const unsigned short* __restrict__ W,
                                                 const float* __restrict__ bias,
                                                 unsigned short* __restrict__ C,
                                                 float scale) {
  __shared__ unsigned short As[128 * 32];  // row-major [row][k], 64B rows (linear for gload)
  __shared__ unsigned short Bs[128 * 32];
  const int m0 = blockIdx.x * 128, n0 = blockIdx.y * 128;
  const int tid = threadIdx.x, wid = tid >> 6, lane = tid & 63;
  const int l15 = lane & 15, lg = lane >> 4;
  const int mb = (wid >> 1) * 64, nb = (wid & 1) * 64;

  f32x4 acc[4][4] = {};

  for (int kk = 0; kk < 32; ++kk) {
    const int k0 = kk * 32;  // element offset in K
#pragma unroll
    for (int i = 0; i < 2; ++i) {
      const int jbase = (wid * 2 + i) * 1024;      // byte base in 8KB tile
      const int o = jbase + lane * 16;             // this lane's byte offset
      const int row = o >> 6, inner = o & 63;      // 64B per row (32 bf16)
      gload16((const char*)A + (size_t)(m0 + row) * 2048 + k0 * 2 + inner,
              (char*)As + jbase);
      gload16((const char*)W + (size_t)(n0 + row) * 2048 + k0 * 2 + inner,
              (char*)Bs + jbase);
    }
    __syncthreads();

    bf16x8 af[4], bfr[4];
#pragma unroll
    for (int ms = 0; ms < 4; ++ms)
      af[ms] = *(const bf16x8*)&As[(mb + ms * 16 + l15) * 32 + lg * 8];
#pragma unroll
    for (int ns = 0; ns < 4; ++ns)
      bfr[ns] = *(const bf16x8*)&Bs[(nb + ns * 16 + l15) * 32 + lg * 8];
#pragma unroll
    for (int ms = 0; ms < 4; ++ms)
#pragma unroll
      for (int ns = 0; ns < 4; ++ns)
        acc[ms][ns] = __builtin_amdgcn_mfma_f32_16x16x32_bf16(af[ms], bfr[ns],
                                                              acc[ms][ns], 0, 0, 0);
    __syncthreads();
  }

  // epilogue: scatter to [B,H,S,DK] bf16. C row=(lg*4+r), col=l15 per frag.
#pragma unroll
  for (int ms = 0; ms < 4; ++ms) {
#pragma unroll
    for (int ns = 0; ns < 4; ++ns) {
      const int n = n0 + nb + ns * 16 + l15;
      const float bv = bias[n];
#pragma unroll
      for (int r = 0; r < 4; ++r) {
        const int m = m0 + mb + ms * 16 + lg * 4 + r;
        const size_t oi =
            (((size_t)(m >> 11) * NH + (n >> 6)) * S_LEN + (m & 2047)) * DK + (n & 63);
        C[oi] = f2bf((acc[ms][ns][r] + bv) * scale);
      }
    }
  }
}

// ---------------- V transpose: [bh][s][dk] -> [bh][dk][s] -------------------
__global__ __launch_bounds__(256) void transpose_v(const unsigned short* __restrict__ V,
                                                   unsigned short* __restrict__ Vt) {
  const int bh = blockIdx.y, st = blockIdx.x;  // 64 bh x 32 s-tiles of 64
  const unsigned short* Vb = V + (size_t)bh * S_LEN * DK;
  unsigned short* Vtb = Vt + (size_t)bh * DK * S_LEN;
  __shared__ unsigned short T[64][72];
  const int t = threadIdx.x;
  const int row = t >> 2, seg = (t & 3) * 16;
  const uint4* src = (const uint4*)(Vb + (size_t)(st * 64 + row) * DK + seg);
  uint4 v0 = src[0], v1 = src[1];
  *(uint4*)&T[row][seg] = v0;
  *(uint4*)&T[row][seg + 8] = v1;
  __syncthreads();
  union { unsigned short u[16]; uint4 q[2]; } tmp;
#pragma unroll
  for (int j = 0; j < 16; ++j) tmp.u[j] = T[seg + j][row];
  uint4* dst = (uint4*)(Vtb + (size_t)row * S_LEN + st * 64 + seg);
  dst[0] = tmp.q[0];
  dst[1] = tmp.q[1];
}

// ---------------- flash attention, 32x32 swapped-QK^T structure --------------
// grid: (16 q-tiles of 128, 64 bh). 4 waves x 32 q-rows, KVBLK=64, Dk=64.
// Swapped QK^T: sacc = mfma(Kfrag, Qfrag) -> lane holds S[q=l31][32 j-vals]
// -> in-register softmax; P redistributed to PV A-frags via cvt_pk +
// permlane32_swap (T12); defer-max online softmax (T13, THR=8); K/V tiles in
// XOR-swizzled LDS staged by global_load_lds with pre-swizzled source (rule 21),
// double-buffered 2-phase schedule (T3-min).
__global__ __launch_bounds__(256) void attn_fwd(const unsigned short* __restrict__ Q,
                                                const unsigned short* __restrict__ K,
                                                const unsigned short* __restrict__ Vt,
                                                float* __restrict__ Out) {
  const int bh = blockIdx.y, qt = blockIdx.x;
  const unsigned short* Qb = Q + (size_t)bh * S_LEN * DK;
  const char* Kb = (const char*)(K + (size_t)bh * S_LEN * DK);
  const char* Vb = (const char*)(Vt + (size_t)bh * DK * S_LEN);
  float* Ob = Out + (size_t)(bh >> 4) * S_LEN * DMODEL + (bh & 15) * DK;

  __shared__ unsigned short Ks[2][64][64];  // [buf][j][dk], 128B rows, XOR-swizzled slots
  __shared__ unsigned short Vs[2][64][64];  // [buf][dk][j]

  const int tid = threadIdx.x, w = tid >> 6, lane = tid & 63;
  const int l31 = lane & 31, hi = lane >> 5;
  const int q0 = qt * 128 + w * 32;
  const int swz = l31 & 7;

  // Q row in registers: qf[d] = Q[q=l31][dk = d*16 + hi*8 .. +7] (B-frag form)
  bf16x8 qf[4];
  {
    const unsigned short* qp = Qb + (size_t)(q0 + l31) * DK + hi * 8;
#pragma unroll
    for (int d = 0; d < 4; ++d) qf[d] = *(const bf16x8*)(qp + d * 16);
  }

  f32x16 oacc0 = {}, oacc1 = {};   // O[q=crow(r,hi)][dk = l31 + 32*db]
  float m_r = -1e30f, l_r = 0.f;   // running max/denominator for q = l31

  const int srow = lane >> 3;                      // 0..7 (row within 8-row chunk)
  const int sbyte = ((lane & 7) ^ srow) * 16;      // inverse-swizzled 16B slot
  const int krow0 = w * 16;                        // this wave's staging rows

  // prologue: stage tile 0 into buf 0
#pragma unroll
  for (int i = 0; i < 2; ++i) {
    gload16(Kb + (size_t)(krow0 + i * 8 + srow) * 128 + sbyte,
            (char*)&Ks[0][krow0 + i * 8][0]);
    gload16(Vb + (size_t)(krow0 + i * 8 + srow) * 4096 + sbyte,
            (char*)&Vs[0][krow0 + i * 8][0]);
  }
  asm volatile("s_waitcnt vmcnt(0)" ::: "memory");
  __syncthreads();

  int buf = 0;
  for (int it = 0; it < 32; ++it) {
    // issue next tile's loads early (hide HBM under compute)
    if (it < 31) {
      const int j0 = (it + 1) * 64;
#pragma unroll
      for (int i = 0; i < 2; ++i) {
        gload16(Kb + (size_t)(j0 + krow0 + i * 8 + srow) * 128 + sbyte,
                (char*)&Ks[buf ^ 1][krow0 + i * 8][0]);
        gload16(Vb + (size_t)(krow0 + i * 8 + srow) * 4096 + j0 * 2 + sbyte,
                (char*)&Vs[buf ^ 1][krow0 + i * 8][0]);
      }
    }
    const char* ksb = (const char*)&Ks[buf][0][0];
    const char* vsb = (const char*)&Vs[buf][0][0];

    // swapped QK^T: sac[jb] = K[jb*32..+32] . Q^T  (S^T, col = q = l31)
    f32x16 sac0 = {}, sac1 = {};
#pragma unroll
    for (int d = 0; d < 4; ++d) {
      bf16x8 k0 = *(const bf16x8*)(ksb + (size_t)(l31)*128 + ((2 * d + hi) ^ swz) * 16);
      bf16x8 k1 = *(const bf16x8*)(ksb + (size_t)(32 + l31) * 128 + ((2 * d + hi) ^ swz) * 16);
      sac0 = __builtin_amdgcn_mfma_f32_32x32x16_bf16(k0, qf[d], sac0, 0, 0, 0);
      sac1 = __builtin_amdgcn_mfma_f32_32x32x16_bf16(k1, qf[d], sac1, 0, 0, 0);
    }

    // in-register row max over this lane's 32 scores, then cross-half swap
    float pm = sac0[0];
#pragma unroll
    for (int r = 1; r < 16; ++r) pm = fmaxf(pm, sac0[r]);
#pragma unroll
    for (int r = 0; r < 16; ++r) pm = fmaxf(pm, sac1[r]);
    {
      u32x2 t = __builtin_amdgcn_permlane32_swap(bitu(pm), bitu(pm), false, false);
      pm = fmaxf(bitf(t[0]), bitf(t[1]));
    }

    // defer-max (T13): rescale only when max grew > 8 (fires ~iter 0 only)
    if (__any(pm > m_r + 8.f)) {
      const float mn = fmaxf(m_r, pm);
      const float esc = __expf(m_r - mn);
      m_r = mn;
      l_r *= esc;
#pragma unroll
      for (int r = 0; r < 16; ++r) {
        const float er = __shfl(esc, ((r & 3) + 8 * (r >> 2)) + hi * 4);
        oacc0[r] *= er;
        oacc1[r] *= er;
      }
    }

    // P = exp(S - m) in place; row sum (in-register + one swap)
    float ps = 0.f;
#pragma unroll
    for (int r = 0; r < 16; ++r) { const float p = __expf(sac0[r] - m_r); sac0[r] = p; ps += p; }
#pragma unroll
    for (int r = 0; r < 16; ++r) { const float p = __expf(sac1[r] - m_r); sac1[r] = p; ps += p; }
    {
      u32x2 t = __builtin_amdgcn_permlane32_swap(bitu(ps), bitu(ps), false, false);
      ps = bitf(t[0]) + bitf(t[1]);
    }
    l_r += ps;

    // pack P to bf16 + permlane redistribute to PV A-frags (T12), then PV
#pragma unroll
    for (int jb = 0; jb < 2; ++jb) {
      const f32x16& e = jb ? sac1 : sac0;
      unsigned pk[8];
#pragma unroll
      for (int m = 0; m < 8; ++m) pk[m] = cvtpk(e[2 * m], e[2 * m + 1]);
#pragma unroll
      for (int ks = 0; ks < 2; ++ks) {
        u32x2 s02 = __builtin_amdgcn_permlane32_swap(pk[4 * ks], pk[4 * ks + 2], false, false);
        u32x2 s13 = __builtin_amdgcn_permlane32_swap(pk[4 * ks + 1], pk[4 * ks + 3], false, false);
        i32x4 paw = {(int)s02[0], (int)s13[0], (int)s02[1], (int)s13[1]};
        bf16x8 pa = __builtin_bit_cast(bf16x8, paw);
        const int vslot = ((4 * jb + 2 * ks + hi) ^ swz) * 16;
        bf16x8 v0 = *(const bf16x8*)(vsb + (size_t)(l31)*128 + vslot);
        bf16x8 v1 = *(const bf16x8*)(vsb + (size_t)(32 + l31) * 128 + vslot);
        oacc0 = __builtin_amdgcn_mfma_f32_32x32x16_bf16(pa, v0, oacc0, 0, 0, 0);
        oacc1 = __builtin_amdgcn_mfma_f32_32x32x16_bf16(pa, v1, oacc1, 0, 0, 0);
      }
    }

    asm volatile("s_waitcnt vmcnt(0)" ::: "memory");
    __syncthreads();
    buf ^= 1;
  }

  // normalize + store fp32, merged-head layout [b][q][h*64 + dk]
  const float linv = 1.f / l_r;
#pragma unroll
  for (int r = 0; r < 16; ++r) {
    const int cr = (r & 3) + 8 * (r >> 2);
    const float li = __shfl(linv, cr + hi * 4);
    const int qg = q0 + cr + 4 * hi;
    float* op = Ob + (size_t)qg * DMODEL;
    op[l31] = oacc0[r] * li;
    op[32 + l31] = oacc1[r] * li;
  }
}

// ---------------- host launch ------------------------------------------------
extern "C" void kernel_launch(void* const* d_in, const int* in_sizes, int n_in,
                              void* d_out, int out_size, void* d_ws, size_t ws_size,
                              hipStream_t stream) {
  (void)in_sizes; (void)n_in; (void)out_size; (void)ws_size;
  const float* q_in = (const float*)d_in[0];
  const float* k_in = (const float*)d_in[1];
  const float* v_in = (const float*)d_in[2];
  const float* Wq = (const float*)d_in[3];
  const float* bq = (const float*)d_in[4];
  const float* Wk = (const float*)d_in[5];
  const float* bk = (const float*)d_in[6];
  const float* Wv = (const float*)d_in[7];
  const float* bv = (const float*)d_in[8];
  float* out = (float*)d_out;

  char* ws = (char*)d_ws;
  unsigned short* Xbf = (unsigned short*)(ws);                    // 16 MB
  unsigned short* Wbf = (unsigned short*)(ws + 16777216);         // 2 MB
  unsigned short* Qh  = (unsigned short*)(ws + 18874368);         // 16 MB
  unsigned short* Kh  = Qh + 8388608;                             // 16 MB
  unsigned short* Vh  = Kh + 8388608;                             // 16 MB
  unsigned short* Vt  = Vh + 8388608;                             // 16 MB

  const int nX8 = (4 * S_LEN * DMODEL) / 8;   // 1048576
  const int nW8 = (DMODEL * DMODEL) / 8;      // 131072
  const dim3 gGemm(64, 8), gBh(32, 64), gAttn(16, 64);

  cvt_f32_bf16<<<4096, 256, 0, stream>>>(q_in, Xbf, nX8);
  cvt_f32_bf16<<<512, 256, 0, stream>>>(Wq, Wbf, nW8);
  proj_gemm<<<gGemm, 256, 0, stream>>>(Xbf, Wbf, bq, Qh, 0.125f);  // fold 1/sqrt(dk)

  cvt_f32_bf16<<<4096, 256, 0, stream>>>(k_in, Xbf, nX8);
  cvt_f32_bf16<<<512, 256, 0, stream>>>(Wk, Wbf, nW8);
  proj_gemm<<<gGemm, 256, 0, stream>>>(Xbf, Wbf, bk, Kh, 1.0f);

  cvt_f32_bf16<<<4096, 256, 0, stream>>>(v_in, Xbf, nX8);
  cvt_f32_bf16<<<512, 256, 0, stream>>>(Wv, Wbf, nW8);
  proj_gemm<<<gGemm, 256, 0, stream>>>(Xbf, Wbf, bv, Vh, 1.0f);

  transpose_v<<<gBh, 256, 0, stream>>>(Vh, Vt);
  attn_fwd<<<gAttn, 256, 0, stream>>>(Qh, Kh, Vt, out);
}